// Round 1
// baseline (406.504 us; speedup 1.0000x reference)
//
#include <hip/hip_runtime.h>

#define C_BINS 9
#define H_DIM 260
#define WDIM 346
#define B_DIM 16
#define HIDDEN 100
#define NEG_SLOPE 0.1f
#define WH (WDIM * H_DIM)                         /* 89,960 */
#define NUM_VOXELS (2 * C_BINS * WH * B_DIM)      /* 25,908,480 */
#define TABLE_N 32768                             /* intervals over [-1, 1]; TABLE_N+1 entries */

// ---------------------------------------------------------------------------
// Kernel 1: tabulate f(u) = MLP(u) for u on a uniform grid over [-1, 1].
// f is the fixed scalar function: lrelu(u*W1+b1) -> lrelu(.@W2^T+b2) -> .@W3^T+b3
// W2 (100x100 = 40 KB) staged in LDS; inner j-index is wave-uniform -> LDS
// broadcast, no bank conflicts. h1[100] lives in VGPRs (full unroll).
// ---------------------------------------------------------------------------
__global__ __launch_bounds__(256) void build_table_kernel(
    const float* __restrict__ W1, const float* __restrict__ b1,
    const float* __restrict__ W2, const float* __restrict__ b2,
    const float* __restrict__ W3, const float* __restrict__ b3,
    float* __restrict__ table)
{
    __shared__ float sW2[HIDDEN * HIDDEN];
    __shared__ float sW1[HIDDEN], sb1[HIDDEN], sb2[HIDDEN], sW3[HIDDEN];
    const int tid = threadIdx.x;
    for (int i = tid; i < HIDDEN * HIDDEN; i += 256) sW2[i] = W2[i];
    if (tid < HIDDEN) {
        sW1[tid] = W1[tid];
        sb1[tid] = b1[tid];
        sb2[tid] = b2[tid];
        sW3[tid] = W3[tid];
    }
    __syncthreads();

    const int g = blockIdx.x * 256 + tid;
    if (g > TABLE_N) return;
    const float u = -1.0f + (2.0f / (float)TABLE_N) * (float)g;

    float h1[HIDDEN];
#pragma unroll
    for (int j = 0; j < HIDDEN; ++j) {
        float v = fmaf(u, sW1[j], sb1[j]);
        h1[j] = (v >= 0.0f) ? v : NEG_SLOPE * v;
    }

    float acc = b3[0];
    for (int k = 0; k < HIDDEN; ++k) {
        float a = sb2[k];
        const float* __restrict__ row = &sW2[k * HIDDEN];
#pragma unroll
        for (int j = 0; j < HIDDEN; ++j) a = fmaf(row[j], h1[j], a);
        a = (a >= 0.0f) ? a : NEG_SLOPE * a;
        acc = fmaf(a, sW3[k], acc);
    }
    table[g] = acc;
}

// ---------------------------------------------------------------------------
// Kernel 2: one thread per event; 9 bins -> 9 table interps + 9 atomicAdds.
// Table (128 KB) stays hot in L2. Input loads are fully coalesced.
// ---------------------------------------------------------------------------
__global__ __launch_bounds__(256) void scatter_kernel(
    const int* __restrict__ xs, const int* __restrict__ ys,
    const float* __restrict__ ts, const int* __restrict__ ps,
    const int* __restrict__ bs, const float* __restrict__ table,
    float* __restrict__ out, int E)
{
    const int e = blockIdx.x * 256 + threadIdx.x;
    if (e >= E) return;

    const int   x = xs[e];
    const int   y = ys[e];
    const int   p = ps[e];
    const int   b = bs[e];
    const float t = ts[e];

    // idx0 = x + W*y + W*H*C*p + 2*W*H*C*b   (all < 2^31)
    int idx0 = x + WDIM * y + (WH * C_BINS) * p + (2 * WH * C_BINS) * b;

#pragma unroll
    for (int i = 0; i < C_BINS; ++i) {
        // u = t - i/8  in [-1, 1): exact (i/8 exactly representable)
        float u   = t - (float)i * (1.0f / (float)(C_BINS - 1));
        float pos = (u + 1.0f) * ((float)TABLE_N * 0.5f);
        int   i0  = (int)pos;
        i0 = (i0 < 0) ? 0 : ((i0 > TABLE_N - 1) ? TABLE_N - 1 : i0);
        float frac = pos - (float)i0;
        float t0 = table[i0];
        float t1 = table[i0 + 1];
        float f  = fmaf(frac, t1 - t0, t0);
        float val = t * f;

        int idx = idx0 + WH * i;
        idx = (idx < 0) ? 0 : ((idx >= NUM_VOXELS) ? NUM_VOXELS - 1 : idx);
        atomicAdd(&out[idx], val);
    }
}

extern "C" void kernel_launch(void* const* d_in, const int* in_sizes, int n_in,
                              void* d_out, int out_size, void* d_ws, size_t ws_size,
                              hipStream_t stream)
{
    const int*   xs = (const int*)d_in[0];
    const int*   ys = (const int*)d_in[1];
    const float* ts = (const float*)d_in[2];
    const int*   ps = (const int*)d_in[3];
    const int*   bs = (const int*)d_in[4];
    const float* W1 = (const float*)d_in[5];
    const float* b1 = (const float*)d_in[6];
    const float* W2 = (const float*)d_in[7];
    const float* b2 = (const float*)d_in[8];
    const float* W3 = (const float*)d_in[9];
    const float* b3 = (const float*)d_in[10];

    float* out   = (float*)d_out;
    float* table = (float*)d_ws;   // needs (TABLE_N+1)*4 = 131,076 B of scratch
    const int E  = in_sizes[0];

    // Zero the voxel grid (harness poisons d_out with 0xAA before every call).
    hipMemsetAsync(d_out, 0, (size_t)out_size * sizeof(float), stream);

    // Tabulate the scalar MLP.
    build_table_kernel<<<(TABLE_N + 1 + 255) / 256, 256, 0, stream>>>(
        W1, b1, W2, b2, W3, b3, table);

    // Scatter-add all events x bins.
    scatter_kernel<<<(E + 255) / 256, 256, 0, stream>>>(
        xs, ys, ts, ps, bs, table, out, E);
}

// Round 2
// 395.234 us; speedup vs baseline: 1.0285x; 1.0285x over previous
//
#include <hip/hip_runtime.h>

#define C_BINS 9
#define H_DIM 260
#define WDIM 346
#define B_DIM 16
#define N_PER_B 32768
#define HIDDEN 100
#define NEG_SLOPE 0.1f
#define WH (WDIM * H_DIM)                         /* 89,960 */
#define NUM_VOXELS (2 * C_BINS * WH * B_DIM)      /* 25,908,480 */
#define TABLE_N 32768                             /* intervals over [-1, 1]; TABLE_N+1 entries */

// ---------------------------------------------------------------------------
// Kernel 0: vectorized zero of the voxel grid (out_size divisible by 4).
// ---------------------------------------------------------------------------
__global__ __launch_bounds__(256) void zero_kernel(float4* __restrict__ out, int n4)
{
    int i = blockIdx.x * 256 + threadIdx.x;
    int stride = gridDim.x * 256;
    float4 z = {0.f, 0.f, 0.f, 0.f};
    for (; i < n4; i += stride) out[i] = z;
}

// ---------------------------------------------------------------------------
// Kernel 1: tabulate f(u) = MLP(u) on a uniform grid over [-1, 1].
// 4 threads per entry (k-dim split 4-ways), 4 independent j-accumulators to
// break the FMA dependency chain, quad shuffle-reduce at the end.
// W2 rows in LDS: lanes read 4 distinct rows (100 floats = 4 banks apart),
// 16-lane broadcast within each row -> conflict-free.
// ---------------------------------------------------------------------------
__global__ __launch_bounds__(256) void build_table_kernel(
    const float* __restrict__ W1, const float* __restrict__ b1,
    const float* __restrict__ W2, const float* __restrict__ b2,
    const float* __restrict__ W3, const float* __restrict__ b3,
    float* __restrict__ table)
{
    __shared__ float sW2[HIDDEN * HIDDEN];
    __shared__ float sW1[HIDDEN], sb1[HIDDEN], sb2[HIDDEN], sW3[HIDDEN];
    const int tid = threadIdx.x;
    for (int i = tid; i < HIDDEN * HIDDEN; i += 256) sW2[i] = W2[i];
    if (tid < HIDDEN) {
        sW1[tid] = W1[tid];
        sb1[tid] = b1[tid];
        sb2[tid] = b2[tid];
        sW3[tid] = W3[tid];
    }
    __syncthreads();

    const int entry_local = tid >> 2;     // 64 entries per block
    const int q = tid & 3;                // k-quarter
    const int g = blockIdx.x * 64 + entry_local;
    if (g > TABLE_N) return;
    const float u = -1.0f + (2.0f / (float)TABLE_N) * (float)g;

    float h1[HIDDEN];
#pragma unroll
    for (int j = 0; j < HIDDEN; ++j) {
        float v = fmaf(u, sW1[j], sb1[j]);
        h1[j] = (v >= 0.0f) ? v : NEG_SLOPE * v;
    }

    float acc = 0.0f;
    for (int k = q; k < HIDDEN; k += 4) {
        const float* __restrict__ row = &sW2[k * HIDDEN];
        float a0 = 0.f, a1 = 0.f, a2 = 0.f, a3 = 0.f;
#pragma unroll
        for (int j = 0; j < HIDDEN; j += 4) {
            a0 = fmaf(row[j + 0], h1[j + 0], a0);
            a1 = fmaf(row[j + 1], h1[j + 1], a1);
            a2 = fmaf(row[j + 2], h1[j + 2], a2);
            a3 = fmaf(row[j + 3], h1[j + 3], a3);
        }
        float a = sb2[k] + ((a0 + a1) + (a2 + a3));
        a = (a >= 0.0f) ? a : NEG_SLOPE * a;
        acc = fmaf(a, sW3[k], acc);
    }
    // reduce across the quad (lanes q=0..3 of this entry)
    acc += __shfl_xor(acc, 1);
    acc += __shfl_xor(acc, 2);
    if (q == 0) table[g] = acc + b3[0];
}

// ---------------------------------------------------------------------------
// Kernel 2: one thread per event; 9 bins -> 9 table interps + 9 atomicAdds.
// Events arrive sorted by batch (bs = repeat(arange(16), 32768)); with 2048
// blocks we swizzle so batch b's 128 blocks all land on XCD b/2 (blocks are
// dispatched round-robin: physical block p -> XCD p%8). Each XCD's atomic
// window shrinks from 103 MB to 13 MB -> L2-local line reuse (~2.9 atomics
// per touched 64B line). Swizzle is locality-only; index math still uses
// the loaded bs[e].
// ---------------------------------------------------------------------------
__global__ __launch_bounds__(256) void scatter_kernel(
    const int* __restrict__ xs, const int* __restrict__ ys,
    const float* __restrict__ ts, const int* __restrict__ ps,
    const int* __restrict__ bs, const float* __restrict__ table,
    float* __restrict__ out, int E)
{
    int e;
    if (gridDim.x == 2048) {
        const int p   = blockIdx.x;
        const int xcd = p & 7;
        const int s   = p >> 3;            // 0..255
        const int bat = 2 * xcd + (s >> 7);
        const int sub = s & 127;
        e = bat * N_PER_B + sub * 256 + threadIdx.x;
    } else {
        e = blockIdx.x * 256 + threadIdx.x;
    }
    if (e >= E) return;

    const int   x = xs[e];
    const int   y = ys[e];
    const int   p = ps[e];
    const int   b = bs[e];
    const float t = ts[e];

    int idx0 = x + WDIM * y + (WH * C_BINS) * p + (2 * WH * C_BINS) * b;

#pragma unroll
    for (int i = 0; i < C_BINS; ++i) {
        float u   = t - (float)i * (1.0f / (float)(C_BINS - 1));
        float pos = (u + 1.0f) * ((float)TABLE_N * 0.5f);
        int   i0  = (int)pos;
        i0 = (i0 < 0) ? 0 : ((i0 > TABLE_N - 1) ? TABLE_N - 1 : i0);
        float frac = pos - (float)i0;
        float t0 = table[i0];
        float t1 = table[i0 + 1];
        float f  = fmaf(frac, t1 - t0, t0);
        float val = t * f;

        int idx = idx0 + WH * i;
        idx = (idx < 0) ? 0 : ((idx >= NUM_VOXELS) ? NUM_VOXELS - 1 : idx);
        atomicAdd(&out[idx], val);
    }
}

extern "C" void kernel_launch(void* const* d_in, const int* in_sizes, int n_in,
                              void* d_out, int out_size, void* d_ws, size_t ws_size,
                              hipStream_t stream)
{
    const int*   xs = (const int*)d_in[0];
    const int*   ys = (const int*)d_in[1];
    const float* ts = (const float*)d_in[2];
    const int*   ps = (const int*)d_in[3];
    const int*   bs = (const int*)d_in[4];
    const float* W1 = (const float*)d_in[5];
    const float* b1 = (const float*)d_in[6];
    const float* W2 = (const float*)d_in[7];
    const float* b2 = (const float*)d_in[8];
    const float* W3 = (const float*)d_in[9];
    const float* b3 = (const float*)d_in[10];

    float* out   = (float*)d_out;
    float* table = (float*)d_ws;   // (TABLE_N+1)*4 = 131,076 B of scratch
    const int E  = in_sizes[0];

    // Zero the voxel grid (harness poisons d_out with 0xAA before every call).
    zero_kernel<<<1024, 256, 0, stream>>>((float4*)out, out_size / 4);

    // Tabulate the scalar MLP: 4 threads per entry, 64 entries per block.
    build_table_kernel<<<(TABLE_N + 1 + 63) / 64, 256, 0, stream>>>(
        W1, b1, W2, b2, W3, b3, table);

    // Scatter-add all events x bins.
    scatter_kernel<<<(E + 255) / 256, 256, 0, stream>>>(
        xs, ys, ts, ps, bs, table, out, E);
}